// Round 1
// 143.720 us; speedup vs baseline: 1.0262x; 1.0262x over previous
//
#include <hip/hip_runtime.h>
#include <hip/hip_bf16.h>

// Problem constants
#define B_    2
#define T_    2048
#define C_    1024
#define H_    16
#define D_    64
#define SRCL_ 128

typedef short  short8 __attribute__((ext_vector_type(8)));   // 8 bf16 (4 VGPRs)
typedef float  f32x4  __attribute__((ext_vector_type(4)));
typedef unsigned short ushort4_t __attribute__((ext_vector_type(4)));
typedef unsigned int   uint4v    __attribute__((ext_vector_type(4)));

// Q pre-scale: 0.125 (1/sqrt(64)) * log2(e) so attn can use raw v_exp_f32 (2^x)
#define QSCALE 0.18033688011112042f

__device__ inline unsigned short f2bf(float f) {
    union { float f; unsigned u; } v; v.f = f;
    unsigned r = v.u + 0x7FFFu + ((v.u >> 16) & 1u);   // RNE
    return (unsigned short)(r >> 16);
}

#if __has_builtin(__builtin_amdgcn_exp2f)
#define EXP2F(x) __builtin_amdgcn_exp2f(x)
#else
#define EXP2F(x) exp2f(x)
#endif

// async global->LDS DMA, 16B per lane; LDS dest = uniform base + lane*16
__device__ __forceinline__ void async_ld16(const void* g, void* l) {
    __builtin_amdgcn_global_load_lds(
        (const __attribute__((address_space(1))) unsigned int*)g,
        (__attribute__((address_space(3))) unsigned int*)l, 16, 0, 0);
}

// ---------------------------------------------------------------------------
// Kernel 1: fp32 -> bf16 conversion of x and the three weight matrices.
// ---------------------------------------------------------------------------
__global__ __launch_bounds__(256) void convert_all(
        const float* __restrict__ x,
        const float* __restrict__ wq,
        const float* __restrict__ wk,
        const float* __restrict__ wv,
        unsigned short* __restrict__ xb,
        unsigned short* __restrict__ wb)
{
    const int NX = (B_ * T_ * C_) / 4;
    const int NW = (C_ * C_) / 4;
    int i = blockIdx.x * 256 + threadIdx.x;
    const float4* src;
    ushort4_t* dst;
    if (i < NX)               { src = (const float4*)x;  dst = (ushort4_t*)xb;                }
    else if (i < NX + NW)     { src = (const float4*)wq; dst = (ushort4_t*)wb;                i -= NX; }
    else if (i < NX + 2*NW)   { src = (const float4*)wk; dst = (ushort4_t*)(wb + C_*C_);      i -= NX + NW; }
    else                      { src = (const float4*)wv; dst = (ushort4_t*)(wb + 2*C_*C_);    i -= NX + 2*NW; }
    float4 v = src[i];
    ushort4_t o;
    o.x = f2bf(v.x); o.y = f2bf(v.y); o.z = f2bf(v.z); o.w = f2bf(v.w);
    dst[i] = o;
}

// ---------------------------------------------------------------------------
// Kernel 2: fused QKV projection GEMM.
//  - double-buffered global_load_lds staging, ONE barrier per K-step
//  - LDS union: epilogue stage overlaps the tile buffers (33 KB total ->
//    4 blocks/CU)
//  - outputs all chunk-tiled per (bh, 64-t-tile), 8KB tiles:
//      Q,K: [d-chunk 0..7][t 0..63][8 d]   (Q pre-scaled by QSCALE)
//      V:   permuted chunk layout matching attn's in-register P fragments:
//           t -> chunk c = ((t>>5)<<2)|((t>>2)&3), slot s = (((t>>4)&1)<<2)|(t&3)
//           i.e. chunk c=(4h|q) slot s holds t = 32h + 16*(s>>2) + 4q + (s&3)
//  - epilogue staged per-wave with 520-elem chunk padding (2-way banks),
//    linear dwordx4 global stores
// ---------------------------------------------------------------------------
__global__ __launch_bounds__(256, 4) void gemm_qkv(
        const unsigned short* __restrict__ xb,   // [4096,1024]
        const unsigned short* __restrict__ wb,   // [3072,1024]
        const float* __restrict__ bq,
        const float* __restrict__ bk,
        const float* __restrict__ bv,
        unsigned short* __restrict__ qo,
        unsigned short* __restrict__ kt,
        unsigned short* __restrict__ vt)
{
    // union: [buf0 A 8KB | buf0 B 8KB | buf1 A 8KB | buf1 B 8KB] (32KB)
    //        overlapped after the K-loop by 4 x 8320B per-wave epilogue stages
    __shared__ __align__(16) unsigned short uni[16640];      // 33,280 B

    const int tid  = threadIdx.x;
    const int wave = tid >> 6;
    const int lane = tid & 63;
    const int lane15 = lane & 15;
    const int quad   = lane >> 4;
    const int wm = wave >> 1;
    const int wn = wave & 1;
    const int m0 = (blockIdx.x & 31) * 128;
    const int n0 = (blockIdx.x >> 5) * 128;

    f32x4 acc[4][4];
#pragma unroll
    for (int mi = 0; mi < 4; ++mi)
#pragma unroll
        for (int ni = 0; ni < 4; ++ni)
            acc[mi][ni] = (f32x4){0.f, 0.f, 0.f, 0.f};

    // staging: 8 x 1KB chunks per matrix per K-step; wave w issues chunks 2w,2w+1
    const int c0   = wave * 2;
    const int rowi0 = 16 * c0 + (lane >> 2);
    const int rowi1 = 16 * (c0 + 1) + (lane >> 2);
    const int col8 = (lane & 3) * 8;

    const unsigned short* xrow0 = &xb[(m0 + rowi0) * 1024 + col8];
    const unsigned short* xrow1 = &xb[(m0 + rowi1) * 1024 + col8];
    const unsigned short* wrow0 = &wb[(n0 + rowi0) * 1024 + col8];
    const unsigned short* wrow1 = &wb[(n0 + rowi1) * 1024 + col8];

    // prologue: K-step 0 -> buf 0
    async_ld16(xrow0, &uni[c0 * 512]);
    async_ld16(xrow1, &uni[(c0 + 1) * 512]);
    async_ld16(wrow0, &uni[4096 + c0 * 512]);
    async_ld16(wrow1, &uni[4096 + (c0 + 1) * 512]);

    for (int it = 0; it < 32; ++it) {
        // all of this tile's DMAs done (own vmcnt(0) x all waves + barrier);
        // also proves every wave finished reading the OTHER buffer.
        __asm__ volatile("s_waitcnt vmcnt(0)\n\ts_barrier" ::: "memory");

        if (it + 1 < 32) {
            const int k1 = (it + 1) * 32;
            unsigned short* nb = &uni[((it + 1) & 1) * 8192];
            async_ld16(xrow0 + k1, &nb[c0 * 512]);
            async_ld16(xrow1 + k1, &nb[(c0 + 1) * 512]);
            async_ld16(wrow0 + k1, &nb[4096 + c0 * 512]);
            async_ld16(wrow1 + k1, &nb[4096 + (c0 + 1) * 512]);
        }

        const unsigned short* As = &uni[(it & 1) * 8192];
        const unsigned short* Bs = As + 4096;

        short8 a[4], bf[4];
#pragma unroll
        for (int mi = 0; mi < 4; ++mi)
            a[mi] = *(const short8*)&As[(wm * 64 + mi * 16 + lane15) * 32 + quad * 8];
#pragma unroll
        for (int ni = 0; ni < 4; ++ni)
            bf[ni] = *(const short8*)&Bs[(wn * 64 + ni * 16 + lane15) * 32 + quad * 8];
#pragma unroll
        for (int mi = 0; mi < 4; ++mi)
#pragma unroll
            for (int ni = 0; ni < 4; ++ni)
                acc[mi][ni] = __builtin_amdgcn_mfma_f32_16x16x32_bf16(a[mi], bf[ni], acc[mi][ni], 0, 0, 0);
    }

    __syncthreads();   // all waves done with tile buffers -> safe to overlay Es

    // ---- epilogue ----
    const int colbase = n0 + wn * 64;
    const int which   = colbase >> 10;            // 0=q 1=k 2=v (wave-uniform)
    const int jj0     = colbase & 1023;
    const int h       = jj0 >> 6;
    const int rowbase = m0 + wm * 64;
    const int bidx    = rowbase >> 11;
    const int t0      = rowbase & 2047;
    const size_t bh   = (size_t)bidx * H_ + h;
    const float* bias_p = (which == 0 ? bq : (which == 1 ? bk : bv)) + jj0;
    const float oscale  = (which == 0) ? QSCALE : 1.0f;

    unsigned short* stage = &uni[wave * 4160];    // 8 chunks x 520 elems

    if (which != 2) {
        // Q/K chunk-tiled: pos = (d>>3)*520 + t*8 + (d&7)
#pragma unroll
        for (int ni = 0; ni < 4; ++ni) {
            const float bias = bias_p[ni * 16 + lane15];
            const int d = ni * 16 + lane15;
            const int dbase = (d >> 3) * 520 + (d & 7);
#pragma unroll
            for (int mi = 0; mi < 4; ++mi)
#pragma unroll
                for (int r = 0; r < 4; ++r) {
                    const int tt = mi * 16 + quad * 4 + r;
                    stage[dbase + tt * 8] = f2bf((acc[mi][ni][r] + bias) * oscale);
                }
        }
    } else {
        // V permuted chunk-tiled: chunk c = (mi>>1)*4 + quad, slot s = (mi&1)*4 + r
        // so that attn's in-register P fragments (keys 16*(e>>2)+4q+(e&3) [+32])
        // line up with vf's k-slots with NO cross-lane P redistribution.
#pragma unroll
        for (int ni = 0; ni < 4; ++ni) {
            const float bias = bias_p[ni * 16 + lane15];
            const int d = ni * 16 + lane15;
#pragma unroll
            for (int mi = 0; mi < 4; ++mi)
#pragma unroll
                for (int r = 0; r < 4; ++r) {
                    const int tt = mi * 16 + quad * 4 + r;
                    const int c  = ((tt >> 5) << 2) | ((tt >> 2) & 3);
                    const int s  = (((tt >> 4) & 1) << 2) | (tt & 3);
                    stage[c * 520 + d * 8 + s] = f2bf(acc[mi][ni][r] + bias);
                }
        }
    }

    unsigned short* gdst =
        (which == 0 ? qo : (which == 1 ? kt : vt)) + bh * (size_t)(T_ * D_) + (t0 >> 6) * 4096;

    // same-wave LDS in-order: no barrier needed before reading own stage
#pragma unroll
    for (int c = 0; c < 8; ++c) {
        *(short8*)&gdst[(c * 64 + lane) * 8] = *(const short8*)&stage[c * 520 + lane * 8];
    }
}

// ---------------------------------------------------------------------------
// Kernel 3: flash attention, block-shared double-buffered K/V LDS staging via
// global_load_lds DMA, SINGLE barrier per tile (wait-barrier-then-issue),
// no-max softmax (scores bounded), O epilogue via LDS linear stores.
// Block = (bh, 64 q-rows); 4 waves x 16 q-rows share staged K/V tiles.
// P stays ENTIRELY in registers: packed bf16 words feed PV's B operand
// directly; V's global layout (gemm epilogue) was permuted to match.
// LDS = 32KB -> 4 blocks/CU resident (was 44KB -> 3).
// ---------------------------------------------------------------------------
__global__ __launch_bounds__(256, 4) void attn(
        const unsigned short* __restrict__ qg,   // chunk-tiled Q (pre-scaled)
        const unsigned short* __restrict__ kg,   // chunk-tiled K
        const unsigned short* __restrict__ vg,   // permuted chunk-tiled V
        float* __restrict__ out)                 // [B,T,C] fp32
{
    __shared__ __align__(16) unsigned short stage[2][8192];  // [buf][K 8KB | V 8KB]

    const int tid  = threadIdx.x;
    const int wave = tid >> 6;
    const int lane = tid & 63;
    const int lane15 = lane & 15;
    const int quad   = lane >> 4;

    const int bh = blockIdx.x & 31;
    const int a  = 31 - (blockIdx.x >> 5);       // heavy q-blocks first
    const int b  = bh >> 4;
    const int h  = bh & 15;
    const int i0 = a * 64 + wave * 16;           // this wave's q rows

    const unsigned short* Q  = qg + (size_t)bh * T_ * D_;
    const unsigned short* KT = kg + (size_t)bh * T_ * D_;
    const unsigned short* VT = vg + (size_t)bh * T_ * D_;

    // Q fragments from chunk-tiled layout: [qtile a][d-chunk][t][8d]
    const int qrow = wave * 16 + lane15;
    const short8 qf0 = *(const short8*)&Q[a * 4096 + quad * 512 + qrow * 8];
    const short8 qf1 = *(const short8*)&Q[a * 4096 + (4 + quad) * 512 + qrow * 8];

    f32x4 o_acc[4];
#pragma unroll
    for (int di = 0; di < 4; ++di) o_acc[di] = (f32x4){0.f, 0.f, 0.f, 0.f};
    float l_p = 0.f;

    const int ntiles = min(a + 3, 32);           // key tiles for this q-block
    const int limit  = i0 + lane15 + SRCL_;

    // DMA of one 16KB tile-pair: 16 x 1KB instrs; wave w issues instrs 4w..4w+3
    const int ib = wave * 4;
    const int loff = lane * 8;

    // prologue: tile 0 -> buf 0
#pragma unroll
    for (int c = 0; c < 4; ++c) {
        const int i = ib + c;
        const unsigned short* src = (i < 8) ? &KT[i * 512 + loff]
                                            : &VT[(i - 8) * 512 + loff];
        async_ld16(src, &stage[0][i * 512]);
    }

    for (int it = 0; it < ntiles; ++it) {
        // own 4 DMAs done + all waves past compute of the other buffer
        __asm__ volatile("s_waitcnt vmcnt(0)\n\ts_barrier" ::: "memory");

        if (it + 1 < ntiles) {
            unsigned short* nb = &stage[(it + 1) & 1][0];
            const size_t tb = (size_t)(it + 1) * 4096;
#pragma unroll
            for (int c = 0; c < 4; ++c) {
                const int i = ib + c;
                const unsigned short* src = (i < 8) ? &KT[tb + i * 512 + loff]
                                                    : &VT[tb + (i - 8) * 512 + loff];
                async_ld16(src, &nb[i * 512]);
            }
        }

        const unsigned short* sb = &stage[it & 1][0];
        const int j0 = it << 6;

        // ---- S^T = K Q^T
        f32x4 sv[4];
#pragma unroll
        for (int ni = 0; ni < 4; ++ni) {
            const short8 kf0 = *(const short8*)&sb[quad * 512 + (ni * 16 + lane15) * 8];
            const short8 kf1 = *(const short8*)&sb[(4 + quad) * 512 + (ni * 16 + lane15) * 8];
            f32x4 t = (f32x4){0.f, 0.f, 0.f, 0.f};
            t = __builtin_amdgcn_mfma_f32_16x16x32_bf16(kf0, qf0, t, 0, 0, 0);
            t = __builtin_amdgcn_mfma_f32_16x16x32_bf16(kf1, qf1, t, 0, 0, 0);
            sv[ni] = t;
        }

        if (j0 + 63 > i0 + SRCL_) {               // boundary tiles only
#pragma unroll
            for (int ni = 0; ni < 4; ++ni)
#pragma unroll
                for (int r = 0; r < 4; ++r) {
                    const int key = j0 + ni * 16 + quad * 4 + r;
                    if (key > limit) sv[ni][r] = -INFINITY;
                }
        }

        // ---- softmax numerators -> packed bf16 P fragments (in registers)
        // lane (quad,lane15) holds P^T[key = j0 + ni*16 + 4*quad + r][q=lane15];
        // pf0 element e -> key 16*(e>>2) + 4*quad + (e&3), pf1 -> +32.
        // V was stored (gemm epilogue) with exactly this t->(chunk,slot) map.
        float lacc = 0.f;
        unsigned pw[8];
#pragma unroll
        for (int ni = 0; ni < 4; ++ni) {
            const float p0 = EXP2F(sv[ni][0]);
            const float p1 = EXP2F(sv[ni][1]);
            const float p2 = EXP2F(sv[ni][2]);
            const float p3 = EXP2F(sv[ni][3]);
            lacc += (p0 + p1) + (p2 + p3);
            const unsigned u0 = __float_as_uint(p0) + 0x8000u;
            const unsigned u1 = __float_as_uint(p1) + 0x8000u;
            const unsigned u2 = __float_as_uint(p2) + 0x8000u;
            const unsigned u3 = __float_as_uint(p3) + 0x8000u;
            pw[ni * 2]     = __builtin_amdgcn_perm(u1, u0, 0x07060302);
            pw[ni * 2 + 1] = __builtin_amdgcn_perm(u3, u2, 0x07060302);
        }
        l_p += lacc;

        const uint4v w0 = {pw[0], pw[1], pw[2], pw[3]};
        const uint4v w1 = {pw[4], pw[5], pw[6], pw[7]};
        const short8 pf0 = __builtin_bit_cast(short8, w0);
        const short8 pf1 = __builtin_bit_cast(short8, w1);

        // ---- V fragments + PV
#pragma unroll
        for (int di = 0; di < 4; ++di) {
            const short8 vf0 = *(const short8*)&sb[4096 + quad * 512 + (di * 16 + lane15) * 8];
            const short8 vf1 = *(const short8*)&sb[4096 + (4 + quad) * 512 + (di * 16 + lane15) * 8];
            o_acc[di] = __builtin_amdgcn_mfma_f32_16x16x32_bf16(vf0, pf0, o_acc[di], 0, 0, 0);
            o_acc[di] = __builtin_amdgcn_mfma_f32_16x16x32_bf16(vf1, pf1, o_acc[di], 0, 0, 0);
        }
    }

    __syncthreads();   // stage reuse as O scratch across waves

    float l0s = l_p + __shfl_xor(l_p, 16);
    const float inv = 1.0f / (l0s + __shfl_xor(l0s, 32));

    float* myOs = (float*)&stage[0][0] + wave * 2048;   // 8KB per wave
#pragma unroll
    for (int di = 0; di < 4; ++di) {
        f32x4 v = o_acc[di] * inv;
        *(f32x4*)&myOs[lane15 * 68 + di * 16 + quad * 4] = v;   // [q][d]
    }
    float* orow0 = out + ((size_t)(b * T_ + i0)) * C_ + h * 64;
#pragma unroll
    for (int c = 0; c < 4; ++c) {
        const int idx = c * 64 + lane;
        const int t   = idx >> 4;
        const int dc  = (idx & 15) * 4;
        float4 v = *(float4*)&myOs[t * 68 + dc];
        *(float4*)(orow0 + (size_t)t * C_ + dc) = v;
    }
}

// ---------------------------------------------------------------------------
// Launch
// ---------------------------------------------------------------------------
extern "C" void kernel_launch(void* const* d_in, const int* in_sizes, int n_in,
                              void* d_out, int out_size, void* d_ws, size_t ws_size,
                              hipStream_t stream) {
    const float* x  = (const float*)d_in[0];
    const float* Wq = (const float*)d_in[1];
    const float* bq = (const float*)d_in[2];
    const float* Wk = (const float*)d_in[3];
    const float* bk = (const float*)d_in[4];
    const float* Wv = (const float*)d_in[5];
    const float* bv = (const float*)d_in[6];
    float* out = (float*)d_out;

    unsigned short* xb  = (unsigned short*)d_ws;            // 4096*1024
    unsigned short* wb  = xb  + (size_t)B_ * T_ * C_;       // 3*1024*1024
    unsigned short* qb  = wb  + (size_t)3 * C_ * C_;        // chunk-tiled Q
    unsigned short* ktb = qb  + (size_t)B_ * H_ * T_ * D_;  // chunk-tiled K
    unsigned short* vtb = ktb + (size_t)B_ * H_ * T_ * D_;  // permuted chunk-tiled V
    ktb = ktb; vtb = vtb;

    convert_all<<<7168, 256, 0, stream>>>(x, Wq, Wk, Wv, xb, wb);
    gemm_qkv<<<768, 256, 0, stream>>>(xb, wb, bq, bk, bv, qb, ktb, vtb);
    attn<<<1024, 256, 0, stream>>>(qb, ktb, vtb, out);
}